// Round 26
// baseline (159.680 us; speedup 1.0000x reference)
//
#include <hip/hip_runtime.h>
#include <hip/hip_bf16.h>

#define CEIL(a, b) (((a) + (b) - 1) / (b))

typedef __hip_bfloat16 bf16;
typedef __attribute__((ext_vector_type(2))) _Float16 h16x2;

// ---------------------------------------------------------------------------
// Corr_upsample_resize_norm: 6-level correlation pyramid.
// INPUT ORDER: x0, xp0, x1, xp1, ..., x5, xp5, motion_state (f32).
// OUTPUT: float32, out_size = 10,948,122: [dw0, corr0, dw1, corr1, ...].
// FUSED LAUNCH PLAN (6 launches):
//   1) k_part_all (1808 x 256; 4 waves/block, wid = blk*4 + tid>>6):
//      corr0s (wid 0..3071, XCD remap, c-loop unroll 2) ||
//      lc1p (3072..6143) || lcrow_all (6144..7231).
//   2) k_red2 (6336 x 256): corr0red (0..5831) || red_all (5832..6335).
//   3) k_expand_all  4) k_finmax  5) k_norm_all  6) k_norm0_tail.
// Scratch map (audited disjoint under fusion):
//   dw0 region: lc1@0[115200], lc2@115200, lc3@125568, lc4@128160,
//     lc5@128808 (ends 128970); P2@200000[331776], P3@600000[82944],
//     P4@700000[20736], P5@730000[5184] (ends 735184);
//     maxbuf@1400000[34992]; uint slots[6]@1492986.
//   part0 (corr0s partials): bf16[11943936] @ f32-elem 2985984, ends
//     8957952; consumed by corr0red (launch 2) before expand overwrites.
//   part1 (lc1 partials):   bf16[3686400]  @ f32-elem 8957952, ends
//     10801152; consumed by red_all (launch 2) before expand overwrites.
// ---------------------------------------------------------------------------

__global__ __launch_bounds__(256) void k_part_all(
    const float* __restrict__ x0, const float* __restrict__ q0,
    const float* __restrict__ x1, const float* __restrict__ q1,
    const float* __restrict__ x2, const float* __restrict__ q2,
    const float* __restrict__ x3, const float* __restrict__ q3,
    const float* __restrict__ x4, const float* __restrict__ q4,
    const float* __restrict__ x5, const float* __restrict__ q5,
    bf16* __restrict__ part0, bf16* __restrict__ part1,
    float* __restrict__ out) {
  const int wid = blockIdx.x * 4 + (threadIdx.x >> 6);
  const int l = threadIdx.x & 63;

  if (wid < 3072) {
    // ---- corr0s. XCD remap: physical XCD ~= (wid>>2)&7 = k; waves on
    // XCD k cover y in [12k,12k+12) x 32 (xt,gc,b) combos. ----
    const int blk = wid >> 2;
    const int s = wid & 3;
    const int k = blk & 7;
    const int m = blk >> 3;
    const int idx = m * 4 + s;       // 0..383
    const int y = k * 12 + (idx % 12);
    const int rest = idx / 12;       // 0..31
    const int xt = rest & 1;
    const int zz = rest >> 1;
    const int gc = zz >> 1;
    const int b = zz & 1;
    const int x0b = xt * 48;

    float acc[9][9];
#pragma unroll
    for (int j = 0; j < 9; ++j)
#pragma unroll
      for (int i = 0; i < 9; ++i) acc[j][i] = 0.f;

    const int xa = x0b - 4 + l;
    const bool ok_a = (l < 56) && (xa >= 0) && (xa < 96);
    const int aoff = y * 96 + (xa < 0 ? 0 : (xa > 95 ? 95 : xa));
    const int xv = x0b + (l < 48 ? l : 47);
    bool okv[9];
    int voff[9];
#pragma unroll
    for (int t = 0; t < 9; ++t) {
      int yy = y - 4 + t;
      okv[t] = (l < 48) && (yy >= 0) && (yy < 96);
      voff[t] = (yy < 0 ? 0 : (yy > 95 ? 95 : yy)) * 96 + xv;
    }

    const float* f1b = x0 + (size_t)b * 512 * 9216;
    const float* f2b = q0 + (size_t)b * 512 * 9216;
    const int c0 = gc * 64;
#pragma unroll 2
    for (int c = c0; c < c0 + 64; c += 2) {
      float a0 = f1b[(size_t)c * 9216 + aoff];
      float a1 = f1b[(size_t)(c + 1) * 9216 + aoff];
      unsigned au =
          __builtin_bit_cast(unsigned, __builtin_amdgcn_cvt_pkrtz(a0, a1));
      au = ok_a ? au : 0u;
      unsigned asu[9];
#pragma unroll
      for (int i = 0; i < 9; ++i)
        asu[i] = (i == 8) ? au : (unsigned)__shfl((int)au, l + 8 - i);
      unsigned vus[9];
#pragma unroll
      for (int t = 0; t < 9; ++t) {
        float v0 = f2b[(size_t)c * 9216 + voff[t]];
        float v1 = f2b[(size_t)(c + 1) * 9216 + voff[t]];
        unsigned vu =
            __builtin_bit_cast(unsigned, __builtin_amdgcn_cvt_pkrtz(v0, v1));
        vus[t] = okv[t] ? vu : 0u;
      }
#pragma unroll
      for (int j = 0; j < 9; ++j) {
        h16x2 vp = __builtin_bit_cast(h16x2, vus[j]);
#pragma unroll
        for (int i = 0; i < 9; ++i)
          acc[j][i] = __builtin_amdgcn_fdot2(
              __builtin_bit_cast(h16x2, asu[i]), vp, acc[j][i], false);
      }
    }

    if (l < 48) {
      size_t base = ((size_t)((gc * 2 + b) * 96 + y)) * 7776 + x0b + l;
#pragma unroll
      for (int j = 0; j < 9; ++j)
#pragma unroll
        for (int i = 0; i < 9; ++i)
          part0[base + (size_t)(j * 9 + i) * 96] = __float2bfloat16(acc[j][i]);
    }
  } else if (wid < 6144) {
    // ---- lc1p (level 1 partials, bf16 out) ----
    const int id2 = wid - 3072;
    const int Y = id2 % 48;
    const int gg = id2 / 48;
    const int gc = gg & 31;
    const int b = gg >> 5;
    const int X = l;
    const bool xin = (X < 48);

    float acc2[5][5];
#pragma unroll
    for (int i = 0; i < 5; ++i)
#pragma unroll
      for (int j = 0; j < 5; ++j) acc2[i][j] = 0.f;

    bool okdy[5];
    int voff[5];
#pragma unroll
    for (int dy = 0; dy < 5; ++dy) {
      int YY = Y + dy - 2;
      okdy[dy] = (YY >= 0 && YY < 48) && xin;
      voff[dy] = (YY < 0 ? 0 : (YY > 47 ? 47 : YY)) * 48 + (xin ? X : 0);
    }
    const float* p1 = x1 + (size_t)b * 1024 * 2304 + Y * 48;
    const float* p2 = q1 + (size_t)b * 1024 * 2304;

    const int c0 = gc * 32;
#pragma unroll 2
    for (int c = c0; c < c0 + 32; c += 2) {
      float a0 = xin ? p1[(size_t)c * 2304 + X] : 0.f;
      float a1 = xin ? p1[(size_t)(c + 1) * 2304 + X] : 0.f;
      unsigned au =
          __builtin_bit_cast(unsigned, __builtin_amdgcn_cvt_pkrtz(a0, a1));
      unsigned asu[5];
#pragma unroll
      for (int dx = 0; dx < 5; ++dx) {
        int src = X - dx + 2;
        src = src < 0 ? 0 : (src > 63 ? 63 : src);
        asu[dx] = (dx == 2) ? au : (unsigned)__shfl((int)au, src);
      }
#pragma unroll
      for (int dy = 0; dy < 5; ++dy) {
        float v0 = p2[(size_t)c * 2304 + voff[dy]];
        float v1 = p2[(size_t)(c + 1) * 2304 + voff[dy]];
        unsigned vu =
            __builtin_bit_cast(unsigned, __builtin_amdgcn_cvt_pkrtz(v0, v1));
        vu = okdy[dy] ? vu : 0u;
        h16x2 vp = __builtin_bit_cast(h16x2, vu);
#pragma unroll
        for (int dx = 0; dx < 5; ++dx)
          acc2[dy][dx] = __builtin_amdgcn_fdot2(
              __builtin_bit_cast(h16x2, asu[dx]), vp, acc2[dy][dx], false);
      }
    }

    bf16* pb = part1 + ((size_t)(gc * 2 + b) * 25) * 2304 + Y * 48;
#pragma unroll
    for (int dy = 0; dy < 5; ++dy)
#pragma unroll
      for (int dx = 0; dx < 5; ++dx) {
        int src = X + dx - 2;
        int scl = src < 0 ? 0 : (src > 63 ? 63 : src);
        float val = __shfl(acc2[dy][dx], scl);
        bool okx = (X + dx - 2 >= 0) && (X + dx - 2 < 48);
        bool oky = (Y + dy - 2 >= 0) && (Y + dy - 2 < 48);
        if (xin)
          pb[(size_t)(dy * 5 + dx) * 2304 + X] =
              __float2bfloat16((oky && okx) ? val : 0.f);
      }
  } else {
    // ---- lcrow_all (levels 2..5 partials, f32 out) ----
    const int id3 = wid - 6144;
    int bx = id3 % 17;
    const int gg = id3 / 17;
    const int gc = gg & 31;
    const int b = gg >> 5;
    int S, C, RW;
    const float *f1, *f2;
    float* part;
    if (bx < 12) {
      S = 24; C = 512; RW = 2; f1 = x2; f2 = q2; part = out + 200000;
    } else if (bx < 15) {
      bx -= 12; S = 12; C = 256; RW = 5; f1 = x3; f2 = q3; part = out + 600000;
    } else if (bx < 16) {
      bx -= 15; S = 6; C = 256; RW = 10; f1 = x4; f2 = q4; part = out + 700000;
    } else {
      bx -= 16; S = 3; C = 256; RW = 21; f1 = x5; f2 = q5; part = out + 730000;
    }
    const int cpg = C / 32;
    const int SS = S * S;
    const int yr = l / S;
    const int X = l % S;
    const int y = bx * RW + yr;
    const bool act = (yr < RW) && (y < S);

    float acc[3][3];
#pragma unroll
    for (int i = 0; i < 3; ++i)
#pragma unroll
      for (int j = 0; j < 3; ++j) acc[i][j] = 0.f;

    bool okdx[3], okdy[3];
    int off1[3], off2[3];
#pragma unroll
    for (int i = 0; i < 3; ++i) {
      int xs = X + 1 - i;
      okdx[i] = act && (xs >= 0) && (xs < S);
      off1[i] = (act ? y : 0) * S + (xs < 0 ? 0 : (xs >= S ? S - 1 : xs));
      int yy = y + i - 1;
      okdy[i] = act && (yy >= 0) && (yy < S);
      off2[i] = (yy < 0 ? 0 : (yy >= S ? S - 1 : yy)) * S + X;
    }

    const float* f1b = f1 + (size_t)b * C * SS;
    const float* f2b = f2 + (size_t)b * C * SS;
    const int c0 = gc * cpg;
    for (int c = c0; c < c0 + cpg; c += 2) {
      const float* p = f1b + (size_t)c * SS;
      const float* pn = p + SS;
      const float* q = f2b + (size_t)c * SS;
      const float* qn = q + SS;
      unsigned au[3], vu[3];
#pragma unroll
      for (int i = 0; i < 3; ++i) {
        unsigned u = __builtin_bit_cast(
            unsigned, __builtin_amdgcn_cvt_pkrtz(p[off1[i]], pn[off1[i]]));
        au[i] = okdx[i] ? u : 0u;
        unsigned w = __builtin_bit_cast(
            unsigned, __builtin_amdgcn_cvt_pkrtz(q[off2[i]], qn[off2[i]]));
        vu[i] = okdy[i] ? w : 0u;
      }
#pragma unroll
      for (int dy = 0; dy < 3; ++dy) {
        h16x2 vp = __builtin_bit_cast(h16x2, vu[dy]);
#pragma unroll
        for (int dxi = 0; dxi < 3; ++dxi)
          acc[dy][dxi] = __builtin_amdgcn_fdot2(
              __builtin_bit_cast(h16x2, au[dxi]), vp, acc[dy][dxi], false);
      }
    }

    if (act) {
      size_t base = ((size_t)(gc * 2 + b) * S + y) * 9 * S + X;
#pragma unroll
      for (int dy = 0; dy < 3; ++dy)
#pragma unroll
        for (int dxi = 0; dxi < 3; ++dxi)
          part[base + (size_t)(dy * 3 + dxi) * S] = acc[dy][dxi];
    }
  }
}

// Launch 2: fused reducers. Blocks 0..5831: corr0red; 5832..6335: red_all.
__global__ __launch_bounds__(256) void k_red2(
    const bf16* __restrict__ part0, const bf16* __restrict__ part1,
    float* __restrict__ out, float* __restrict__ maxbuf) {
  if (blockIdx.x < 5832) {
    const int t = blockIdx.x * 256 + threadIdx.x;  // < 1492992 exact
    const int x = t % 96;
    const int y = (t / 96) % 96;
    const int d = (t / 9216) % 81;
    const int b = t / 746496;
    const int dx = d % 9;
    const int xs = x + dx - 4;
    float v = 0.f;
    if (xs >= 0 && xs < 96) {
      size_t base = ((size_t)(b * 96 + y)) * 7776 + (size_t)d * 96 + xs;
      const size_t gstride = (size_t)2 * 96 * 7776;
#pragma unroll
      for (int gc = 0; gc < 8; ++gc)
        v += __bfloat162float(part0[base + gc * gstride]);
    }
    v = v >= 0.f ? v : 0.01f * v;
    out[1492992 + t] = v;
    float mx = v;
#pragma unroll
    for (int off = 32; off; off >>= 1) mx = fmaxf(mx, __shfl_down(mx, off));
    __shared__ float wm[4];
    if ((threadIdx.x & 63) == 0) wm[threadIdx.x >> 6] = mx;
    __syncthreads();
    if (threadIdx.x == 0)
      maxbuf[blockIdx.x] = fmaxf(fmaxf(wm[0], wm[1]), fmaxf(wm[2], wm[3]));
    return;
  }
  int t = (blockIdx.x - 5832) * 256 + threadIdx.x;
  if (t < 115200) {
    const int o = t / 4608;
    const int pix = t % 4608;
    const int b = pix / 2304, r = pix % 2304;
    float s = 0.f;
#pragma unroll
    for (int g = 0; g < 32; ++g)
      s += __bfloat162float(part1[((size_t)(g * 2 + b) * 25 + o) * 2304 + r]);
    out[(size_t)pix * 25 + o] = s;  // lc1 @ 0
    return;
  }
  t -= 115200;
  int S;
  const float* part;
  float* lc;
  if (t < 10368) {
    S = 24; part = out + 200000; lc = out + 115200;
  } else if ((t -= 10368) < 2592) {
    S = 12; part = out + 600000; lc = out + 125568;
  } else if ((t -= 2592) < 648) {
    S = 6; part = out + 700000; lc = out + 128160;
  } else if ((t -= 648) < 162) {
    S = 3; part = out + 730000; lc = out + 128808;
  } else {
    return;
  }
  const int SS = S * S;
  const int o = t % 9;
  const int p = t / 9;
  const int b = p / SS, r = p % SS, y = r / S, X = r % S;
  const int dy = o / 3, dx = o % 3;
  const int xs = X + dx - 1;
  float v = 0.f;
  if (xs >= 0 && xs < S) {
    size_t base = ((size_t)b * S + y) * 9 * S + (size_t)(dy * 3 + dx) * S + xs;
    const size_t gstride = (size_t)2 * S * 9 * S;
#pragma unroll
    for (int g = 0; g < 32; ++g) v += part[base + g * gstride];
  }
  lc[(size_t)p * 9 + o] = v;
}

// Expansion for levels 1..5 (fused): grid (5832, 5), blockIdx.y = lvl-1.
__global__ __launch_bounds__(256) void k_expand_all(
    float* __restrict__ out, float* __restrict__ maxbuf) {
  static const int lcoffs[6] = {0, 0, 115200, 125568, 128160, 128808};
  static const size_t dwo[6] = {0,       2985984, 4852224,
                                6438528, 7954848, 9453672};
  static const size_t cro[6] = {1492992, 3359232, 4945536,
                                6461856, 7960680, 9455130};
  const int lvl = (int)blockIdx.y + 1;
  const int R = (lvl == 1) ? 2 : 1;
  const float* lc = out + lcoffs[lvl];
  float* out_corr = out + cro[lvl];
  float* out_dw = out + dwo[lvl];
  const int t = blockIdx.x * 256 + threadIdx.x;
  float contrib = 0.f;
  {
    const int x = t % 96;
    const int y = (t / 96) % 96;
    const int d = (t / 9216) % 81;
    const int b = t / 746496;
    const int hy = y + d / 9 - 4;
    const int hx = x + d % 9 - 4;
    float val = 0.f;
    if (hy >= 0 && hy < 96 && hx >= 0 && hx < 96) {
      const int S = 96 >> lvl;
      const int Y1 = y >> lvl, X1 = x >> lvl;
      const int oy = (hy >> lvl) - Y1 + R;
      const int ox = (hx >> lvl) - X1 + R;
      const int DD = 2 * R + 1;
      val = lc[(((size_t)(b * S + Y1) * S + X1) * DD + oy) * DD + ox];
      val = val >= 0.f ? val : 0.01f * val;
    }
    out_corr[t] = val;
    const int m = (1 << lvl) - 1;
    if (((y | x) & m) == 0) {
      const int S = 96 >> lvl;
      out_dw[((size_t)(b * 81 + d) * S + (y >> lvl)) * S + (x >> lvl)] = val;
      contrib = val;
    }
  }
#pragma unroll
  for (int off = 32; off; off >>= 1)
    contrib = fmaxf(contrib, __shfl_down(contrib, off));
  __shared__ float wm[4];
  if ((threadIdx.x & 63) == 0) wm[threadIdx.x >> 6] = contrib;
  __syncthreads();
  if (threadIdx.x == 0)
    maxbuf[(size_t)lvl * 5832 + blockIdx.x] =
        fmaxf(fmaxf(wm[0], wm[1]), fmaxf(wm[2], wm[3]));
}

// Reduce per-block maxima (5832 per level) into slots[lvl]. grid(6).
__global__ __launch_bounds__(1024) void k_finmax(
    const float* __restrict__ maxbuf, unsigned int* __restrict__ slots) {
  const int lvl = blockIdx.x;
  const float* mb = maxbuf + (size_t)lvl * 5832;
  float m = 0.f;
  for (int i = threadIdx.x; i < 5832; i += 1024) m = fmaxf(m, mb[i]);
#pragma unroll
  for (int off = 32; off; off >>= 1) m = fmaxf(m, __shfl_down(m, off));
  __shared__ float wm[16];
  if ((threadIdx.x & 63) == 0) wm[threadIdx.x >> 6] = m;
  __syncthreads();
  if (threadIdx.x == 0) {
    float r = wm[0];
#pragma unroll
    for (int i = 1; i < 16; ++i) r = fmaxf(r, wm[i]);
    slots[lvl] = (unsigned int)__float_as_int(r);
  }
}

// All-level normalize (flat segmented, total 1,990,164 threads needed).
__global__ __launch_bounds__(256) void k_norm_all(
    float* __restrict__ out, const unsigned int* __restrict__ slots) {
  int i = blockIdx.x * 256 + threadIdx.x;
  int lvl;
  size_t dst, src;
  if (i < 1492986) {
    lvl = 0; dst = i; src = (size_t)1492992 + i;
  } else if ((i -= 1492986) < 373248) {
    lvl = 1; dst = (size_t)2985984 + i; src = dst;
  } else if ((i -= 373248) < 93312) {
    lvl = 2; dst = (size_t)4852224 + i; src = dst;
  } else if ((i -= 93312) < 23328) {
    lvl = 3; dst = (size_t)6438528 + i; src = dst;
  } else if ((i -= 23328) < 5832) {
    lvl = 4; dst = (size_t)7954848 + i; src = dst;
  } else if ((i -= 5832) < 1458) {
    lvl = 5; dst = (size_t)9453672 + i; src = dst;
  } else {
    return;
  }
  const float m = __int_as_float((int)slots[lvl]);
  out[dst] = out[src] / m;
}

// Last 6 dw0 elements alias the slot bytes: read slot0 first, then write.
__global__ __launch_bounds__(64) void k_norm0_tail(
    float* __restrict__ out, const unsigned int* __restrict__ slots) {
  const float m = __int_as_float((int)slots[0]);
  if (threadIdx.x < 6) {
    const int t = 1492986 + threadIdx.x;
    out[t] = out[1492992 + t] / m;
  }
}

extern "C" void kernel_launch(void* const* d_in, const int* in_sizes, int n_in,
                              void* d_out, int out_size, void* d_ws,
                              size_t ws_size, hipStream_t stream) {
  const float* x[6];
  const float* xp[6];
  for (int i = 0; i < 6; ++i) {
    x[i] = (const float*)d_in[2 * i];
    xp[i] = (const float*)d_in[2 * i + 1];
  }
  float* out = (float*)d_out;

  float* maxbuf = out + 1400000;                         // 34992
  unsigned int* slots = (unsigned int*)(out + 1492986);  // 24 B
  bf16* part0 = (bf16*)(out + 2985984);                  // ends f32 8957952
  bf16* part1 = (bf16*)(out + 8957952);                  // ends f32 10801152

  const int NORM_TOTAL = 1492986 + 373248 + 93312 + 23328 + 5832 + 1458;

  k_part_all<<<dim3(1808), dim3(256), 0, stream>>>(
      x[0], xp[0], x[1], xp[1], x[2], xp[2], x[3], xp[3], x[4], xp[4], x[5],
      xp[5], part0, part1, out);
  k_red2<<<dim3(6336), dim3(256), 0, stream>>>(part0, part1, out, maxbuf);
  k_expand_all<<<dim3(5832, 5), dim3(256), 0, stream>>>(out, maxbuf);
  k_finmax<<<dim3(6), dim3(1024), 0, stream>>>(maxbuf, slots);
  k_norm_all<<<dim3(CEIL(NORM_TOTAL, 256)), dim3(256), 0, stream>>>(out,
                                                                    slots);
  k_norm0_tail<<<dim3(1), dim3(64), 0, stream>>>(out, slots);
}

// Round 27
// 100.915 us; speedup vs baseline: 1.5823x; 1.5823x over previous
//
#include <hip/hip_runtime.h>
#include <hip/hip_bf16.h>

#define CEIL(a, b) (((a) + (b) - 1) / (b))

typedef __hip_bfloat16 bf16;
typedef __attribute__((ext_vector_type(2))) _Float16 h16x2;

// ---------------------------------------------------------------------------
// Corr_upsample_resize_norm: 6-level correlation pyramid.
// INPUT ORDER: x0, xp0, x1, xp1, ..., x5, xp5, motion_state (f32).
// OUTPUT: float32, out_size = 10,948,122: [dw0, corr0, dw1, corr1, ...].
// FUSED LAUNCH PLAN (6 launches):
//   1) k_part_all (1808 x 256; 4 waves/block, wid = blk*4 + tid>>6):
//      corr0s (wid 0..3071, XCD remap) || lc1p (3072..6143) ||
//      lcrow_all (6144..7231). Section boundaries are block-aligned.
//   2) k_red2 (6336 x 256): corr0red (0..5831) || red_all (5832..6335).
//   3) k_expand_all  4) k_finmax  5) k_norm_all  6) k_norm0_tail.
// Scratch map (audited disjoint under fusion):
//   dw0 region: lc1@0[115200], lc2@115200, lc3@125568, lc4@128160,
//     lc5@128808 (ends 128970); P2@200000[331776], P3@600000[82944],
//     P4@700000[20736], P5@730000[5184] (ends 735184);
//     maxbuf@1400000[34992]; uint slots[6]@1492986.
//   part0 (corr0s partials): bf16[11943936] @ f32-elem 2985984, ends
//     8957952; consumed by corr0red (launch 2) before expand overwrites.
//   part1 (lc1 partials):   bf16[3686400]  @ f32-elem 8957952, ends
//     10801152; consumed by red_all (launch 2) before expand overwrites.
// ---------------------------------------------------------------------------

__global__ __launch_bounds__(256) void k_part_all(
    const float* __restrict__ x0, const float* __restrict__ q0,
    const float* __restrict__ x1, const float* __restrict__ q1,
    const float* __restrict__ x2, const float* __restrict__ q2,
    const float* __restrict__ x3, const float* __restrict__ q3,
    const float* __restrict__ x4, const float* __restrict__ q4,
    const float* __restrict__ x5, const float* __restrict__ q5,
    bf16* __restrict__ part0, bf16* __restrict__ part1,
    float* __restrict__ out) {
  const int wid = blockIdx.x * 4 + (threadIdx.x >> 6);
  const int l = threadIdx.x & 63;

  if (wid < 3072) {
    // ---- corr0s. XCD remap for block-granular round-robin: physical XCD
    // ~= (wid>>2)&7 = k; waves on XCD k cover y in [12k, 12k+12) x 32
    // (xt,gc,b) combos. ----
    const int blk = wid >> 2;
    const int s = wid & 3;
    const int k = blk & 7;
    const int m = blk >> 3;
    const int idx = m * 4 + s;       // 0..383
    const int y = k * 12 + (idx % 12);
    const int rest = idx / 12;       // 0..31
    const int xt = rest & 1;
    const int zz = rest >> 1;
    const int gc = zz >> 1;
    const int b = zz & 1;
    const int x0b = xt * 48;

    float acc[9][9];
#pragma unroll
    for (int j = 0; j < 9; ++j)
#pragma unroll
      for (int i = 0; i < 9; ++i) acc[j][i] = 0.f;

    const int xa = x0b - 4 + l;
    const bool ok_a = (l < 56) && (xa >= 0) && (xa < 96);
    const int aoff = y * 96 + (xa < 0 ? 0 : (xa > 95 ? 95 : xa));
    const int xv = x0b + (l < 48 ? l : 47);
    bool okv[9];
    int voff[9];
#pragma unroll
    for (int t = 0; t < 9; ++t) {
      int yy = y - 4 + t;
      okv[t] = (l < 48) && (yy >= 0) && (yy < 96);
      voff[t] = (yy < 0 ? 0 : (yy > 95 ? 95 : yy)) * 96 + xv;
    }

    const float* f1b = x0 + (size_t)b * 512 * 9216;
    const float* f2b = q0 + (size_t)b * 512 * 9216;
    const int c0 = gc * 64;
    for (int c = c0; c < c0 + 64; c += 2) {
      float a0 = f1b[(size_t)c * 9216 + aoff];
      float a1 = f1b[(size_t)(c + 1) * 9216 + aoff];
      unsigned au =
          __builtin_bit_cast(unsigned, __builtin_amdgcn_cvt_pkrtz(a0, a1));
      au = ok_a ? au : 0u;
      unsigned asu[9];
#pragma unroll
      for (int i = 0; i < 9; ++i)
        asu[i] = (i == 8) ? au : (unsigned)__shfl((int)au, l + 8 - i);
      unsigned vus[9];
#pragma unroll
      for (int t = 0; t < 9; ++t) {
        float v0 = f2b[(size_t)c * 9216 + voff[t]];
        float v1 = f2b[(size_t)(c + 1) * 9216 + voff[t]];
        unsigned vu =
            __builtin_bit_cast(unsigned, __builtin_amdgcn_cvt_pkrtz(v0, v1));
        vus[t] = okv[t] ? vu : 0u;
      }
#pragma unroll
      for (int j = 0; j < 9; ++j) {
        h16x2 vp = __builtin_bit_cast(h16x2, vus[j]);
#pragma unroll
        for (int i = 0; i < 9; ++i)
          acc[j][i] = __builtin_amdgcn_fdot2(
              __builtin_bit_cast(h16x2, asu[i]), vp, acc[j][i], false);
      }
    }

    if (l < 48) {
      size_t base = ((size_t)((gc * 2 + b) * 96 + y)) * 7776 + x0b + l;
#pragma unroll
      for (int j = 0; j < 9; ++j)
#pragma unroll
        for (int i = 0; i < 9; ++i)
          part0[base + (size_t)(j * 9 + i) * 96] = __float2bfloat16(acc[j][i]);
    }
  } else if (wid < 6144) {
    // ---- lc1p (level 1 partials, bf16 out) ----
    const int id2 = wid - 3072;
    const int Y = id2 % 48;
    const int gg = id2 / 48;
    const int gc = gg & 31;
    const int b = gg >> 5;
    const int X = l;
    const bool xin = (X < 48);

    float acc2[5][5];
#pragma unroll
    for (int i = 0; i < 5; ++i)
#pragma unroll
      for (int j = 0; j < 5; ++j) acc2[i][j] = 0.f;

    bool okdy[5];
    int voff[5];
#pragma unroll
    for (int dy = 0; dy < 5; ++dy) {
      int YY = Y + dy - 2;
      okdy[dy] = (YY >= 0 && YY < 48) && xin;
      voff[dy] = (YY < 0 ? 0 : (YY > 47 ? 47 : YY)) * 48 + (xin ? X : 0);
    }
    const float* p1 = x1 + (size_t)b * 1024 * 2304 + Y * 48;
    const float* p2 = q1 + (size_t)b * 1024 * 2304;

    const int c0 = gc * 32;
#pragma unroll 2
    for (int c = c0; c < c0 + 32; c += 2) {
      float a0 = xin ? p1[(size_t)c * 2304 + X] : 0.f;
      float a1 = xin ? p1[(size_t)(c + 1) * 2304 + X] : 0.f;
      unsigned au =
          __builtin_bit_cast(unsigned, __builtin_amdgcn_cvt_pkrtz(a0, a1));
      unsigned asu[5];
#pragma unroll
      for (int dx = 0; dx < 5; ++dx) {
        int src = X - dx + 2;
        src = src < 0 ? 0 : (src > 63 ? 63 : src);
        asu[dx] = (dx == 2) ? au : (unsigned)__shfl((int)au, src);
      }
#pragma unroll
      for (int dy = 0; dy < 5; ++dy) {
        float v0 = p2[(size_t)c * 2304 + voff[dy]];
        float v1 = p2[(size_t)(c + 1) * 2304 + voff[dy]];
        unsigned vu =
            __builtin_bit_cast(unsigned, __builtin_amdgcn_cvt_pkrtz(v0, v1));
        vu = okdy[dy] ? vu : 0u;
        h16x2 vp = __builtin_bit_cast(h16x2, vu);
#pragma unroll
        for (int dx = 0; dx < 5; ++dx)
          acc2[dy][dx] = __builtin_amdgcn_fdot2(
              __builtin_bit_cast(h16x2, asu[dx]), vp, acc2[dy][dx], false);
      }
    }

    bf16* pb = part1 + ((size_t)(gc * 2 + b) * 25) * 2304 + Y * 48;
#pragma unroll
    for (int dy = 0; dy < 5; ++dy)
#pragma unroll
      for (int dx = 0; dx < 5; ++dx) {
        int src = X + dx - 2;
        int scl = src < 0 ? 0 : (src > 63 ? 63 : src);
        float val = __shfl(acc2[dy][dx], scl);
        bool okx = (X + dx - 2 >= 0) && (X + dx - 2 < 48);
        bool oky = (Y + dy - 2 >= 0) && (Y + dy - 2 < 48);
        if (xin)
          pb[(size_t)(dy * 5 + dx) * 2304 + X] =
              __float2bfloat16((oky && okx) ? val : 0.f);
      }
  } else {
    // ---- lcrow_all (levels 2..5 partials, f32 out) ----
    const int id3 = wid - 6144;
    int bx = id3 % 17;
    const int gg = id3 / 17;
    const int gc = gg & 31;
    const int b = gg >> 5;
    int S, C, RW;
    const float *f1, *f2;
    float* part;
    if (bx < 12) {
      S = 24; C = 512; RW = 2; f1 = x2; f2 = q2; part = out + 200000;
    } else if (bx < 15) {
      bx -= 12; S = 12; C = 256; RW = 5; f1 = x3; f2 = q3; part = out + 600000;
    } else if (bx < 16) {
      bx -= 15; S = 6; C = 256; RW = 10; f1 = x4; f2 = q4; part = out + 700000;
    } else {
      bx -= 16; S = 3; C = 256; RW = 21; f1 = x5; f2 = q5; part = out + 730000;
    }
    const int cpg = C / 32;
    const int SS = S * S;
    const int yr = l / S;
    const int X = l % S;
    const int y = bx * RW + yr;
    const bool act = (yr < RW) && (y < S);

    float acc[3][3];
#pragma unroll
    for (int i = 0; i < 3; ++i)
#pragma unroll
      for (int j = 0; j < 3; ++j) acc[i][j] = 0.f;

    bool okdx[3], okdy[3];
    int off1[3], off2[3];
#pragma unroll
    for (int i = 0; i < 3; ++i) {
      int xs = X + 1 - i;
      okdx[i] = act && (xs >= 0) && (xs < S);
      off1[i] = (act ? y : 0) * S + (xs < 0 ? 0 : (xs >= S ? S - 1 : xs));
      int yy = y + i - 1;
      okdy[i] = act && (yy >= 0) && (yy < S);
      off2[i] = (yy < 0 ? 0 : (yy >= S ? S - 1 : yy)) * S + X;
    }

    const float* f1b = f1 + (size_t)b * C * SS;
    const float* f2b = f2 + (size_t)b * C * SS;
    const int c0 = gc * cpg;
    for (int c = c0; c < c0 + cpg; c += 2) {
      const float* p = f1b + (size_t)c * SS;
      const float* pn = p + SS;
      const float* q = f2b + (size_t)c * SS;
      const float* qn = q + SS;
      unsigned au[3], vu[3];
#pragma unroll
      for (int i = 0; i < 3; ++i) {
        unsigned u = __builtin_bit_cast(
            unsigned, __builtin_amdgcn_cvt_pkrtz(p[off1[i]], pn[off1[i]]));
        au[i] = okdx[i] ? u : 0u;
        unsigned w = __builtin_bit_cast(
            unsigned, __builtin_amdgcn_cvt_pkrtz(q[off2[i]], qn[off2[i]]));
        vu[i] = okdy[i] ? w : 0u;
      }
#pragma unroll
      for (int dy = 0; dy < 3; ++dy) {
        h16x2 vp = __builtin_bit_cast(h16x2, vu[dy]);
#pragma unroll
        for (int dxi = 0; dxi < 3; ++dxi)
          acc[dy][dxi] = __builtin_amdgcn_fdot2(
              __builtin_bit_cast(h16x2, au[dxi]), vp, acc[dy][dxi], false);
      }
    }

    if (act) {
      size_t base = ((size_t)(gc * 2 + b) * S + y) * 9 * S + X;
#pragma unroll
      for (int dy = 0; dy < 3; ++dy)
#pragma unroll
        for (int dxi = 0; dxi < 3; ++dxi)
          part[base + (size_t)(dy * 3 + dxi) * S] = acc[dy][dxi];
    }
  }
}

// Launch 2: fused reducers. Blocks 0..5831: corr0red; 5832..6335: red_all.
__global__ __launch_bounds__(256) void k_red2(
    const bf16* __restrict__ part0, const bf16* __restrict__ part1,
    float* __restrict__ out, float* __restrict__ maxbuf) {
  if (blockIdx.x < 5832) {
    const int t = blockIdx.x * 256 + threadIdx.x;  // < 1492992 exact
    const int x = t % 96;
    const int y = (t / 96) % 96;
    const int d = (t / 9216) % 81;
    const int b = t / 746496;
    const int dx = d % 9;
    const int xs = x + dx - 4;
    float v = 0.f;
    if (xs >= 0 && xs < 96) {
      size_t base = ((size_t)(b * 96 + y)) * 7776 + (size_t)d * 96 + xs;
      const size_t gstride = (size_t)2 * 96 * 7776;
#pragma unroll
      for (int gc = 0; gc < 8; ++gc)
        v += __bfloat162float(part0[base + gc * gstride]);
    }
    v = v >= 0.f ? v : 0.01f * v;
    out[1492992 + t] = v;
    float mx = v;
#pragma unroll
    for (int off = 32; off; off >>= 1) mx = fmaxf(mx, __shfl_down(mx, off));
    __shared__ float wm[4];
    if ((threadIdx.x & 63) == 0) wm[threadIdx.x >> 6] = mx;
    __syncthreads();
    if (threadIdx.x == 0)
      maxbuf[blockIdx.x] = fmaxf(fmaxf(wm[0], wm[1]), fmaxf(wm[2], wm[3]));
    return;
  }
  int t = (blockIdx.x - 5832) * 256 + threadIdx.x;
  if (t < 115200) {
    const int o = t / 4608;
    const int pix = t % 4608;
    const int b = pix / 2304, r = pix % 2304;
    float s = 0.f;
#pragma unroll
    for (int g = 0; g < 32; ++g)
      s += __bfloat162float(part1[((size_t)(g * 2 + b) * 25 + o) * 2304 + r]);
    out[(size_t)pix * 25 + o] = s;  // lc1 @ 0
    return;
  }
  t -= 115200;
  int S;
  const float* part;
  float* lc;
  if (t < 10368) {
    S = 24; part = out + 200000; lc = out + 115200;
  } else if ((t -= 10368) < 2592) {
    S = 12; part = out + 600000; lc = out + 125568;
  } else if ((t -= 2592) < 648) {
    S = 6; part = out + 700000; lc = out + 128160;
  } else if ((t -= 648) < 162) {
    S = 3; part = out + 730000; lc = out + 128808;
  } else {
    return;
  }
  const int SS = S * S;
  const int o = t % 9;
  const int p = t / 9;
  const int b = p / SS, r = p % SS, y = r / S, X = r % S;
  const int dy = o / 3, dx = o % 3;
  const int xs = X + dx - 1;
  float v = 0.f;
  if (xs >= 0 && xs < S) {
    size_t base = ((size_t)b * S + y) * 9 * S + (size_t)(dy * 3 + dx) * S + xs;
    const size_t gstride = (size_t)2 * S * 9 * S;
#pragma unroll
    for (int g = 0; g < 32; ++g) v += part[base + g * gstride];
  }
  lc[(size_t)p * 9 + o] = v;
}

// Expansion for levels 1..5 (fused): grid (5832, 5), blockIdx.y = lvl-1.
__global__ __launch_bounds__(256) void k_expand_all(
    float* __restrict__ out, float* __restrict__ maxbuf) {
  static const int lcoffs[6] = {0, 0, 115200, 125568, 128160, 128808};
  static const size_t dwo[6] = {0,       2985984, 4852224,
                                6438528, 7954848, 9453672};
  static const size_t cro[6] = {1492992, 3359232, 4945536,
                                6461856, 7960680, 9455130};
  const int lvl = (int)blockIdx.y + 1;
  const int R = (lvl == 1) ? 2 : 1;
  const float* lc = out + lcoffs[lvl];
  float* out_corr = out + cro[lvl];
  float* out_dw = out + dwo[lvl];
  const int t = blockIdx.x * 256 + threadIdx.x;
  float contrib = 0.f;
  {
    const int x = t % 96;
    const int y = (t / 96) % 96;
    const int d = (t / 9216) % 81;
    const int b = t / 746496;
    const int hy = y + d / 9 - 4;
    const int hx = x + d % 9 - 4;
    float val = 0.f;
    if (hy >= 0 && hy < 96 && hx >= 0 && hx < 96) {
      const int S = 96 >> lvl;
      const int Y1 = y >> lvl, X1 = x >> lvl;
      const int oy = (hy >> lvl) - Y1 + R;
      const int ox = (hx >> lvl) - X1 + R;
      const int DD = 2 * R + 1;
      val = lc[(((size_t)(b * S + Y1) * S + X1) * DD + oy) * DD + ox];
      val = val >= 0.f ? val : 0.01f * val;
    }
    out_corr[t] = val;
    const int m = (1 << lvl) - 1;
    if (((y | x) & m) == 0) {
      const int S = 96 >> lvl;
      out_dw[((size_t)(b * 81 + d) * S + (y >> lvl)) * S + (x >> lvl)] = val;
      contrib = val;
    }
  }
#pragma unroll
  for (int off = 32; off; off >>= 1)
    contrib = fmaxf(contrib, __shfl_down(contrib, off));
  __shared__ float wm[4];
  if ((threadIdx.x & 63) == 0) wm[threadIdx.x >> 6] = contrib;
  __syncthreads();
  if (threadIdx.x == 0)
    maxbuf[(size_t)lvl * 5832 + blockIdx.x] =
        fmaxf(fmaxf(wm[0], wm[1]), fmaxf(wm[2], wm[3]));
}

// Reduce per-block maxima (5832 per level) into slots[lvl]. grid(6).
__global__ __launch_bounds__(1024) void k_finmax(
    const float* __restrict__ maxbuf, unsigned int* __restrict__ slots) {
  const int lvl = blockIdx.x;
  const float* mb = maxbuf + (size_t)lvl * 5832;
  float m = 0.f;
  for (int i = threadIdx.x; i < 5832; i += 1024) m = fmaxf(m, mb[i]);
#pragma unroll
  for (int off = 32; off; off >>= 1) m = fmaxf(m, __shfl_down(m, off));
  __shared__ float wm[16];
  if ((threadIdx.x & 63) == 0) wm[threadIdx.x >> 6] = m;
  __syncthreads();
  if (threadIdx.x == 0) {
    float r = wm[0];
#pragma unroll
    for (int i = 1; i < 16; ++i) r = fmaxf(r, wm[i]);
    slots[lvl] = (unsigned int)__float_as_int(r);
  }
}

// All-level normalize (flat segmented, total 1,990,164 threads needed).
__global__ __launch_bounds__(256) void k_norm_all(
    float* __restrict__ out, const unsigned int* __restrict__ slots) {
  int i = blockIdx.x * 256 + threadIdx.x;
  int lvl;
  size_t dst, src;
  if (i < 1492986) {
    lvl = 0; dst = i; src = (size_t)1492992 + i;
  } else if ((i -= 1492986) < 373248) {
    lvl = 1; dst = (size_t)2985984 + i; src = dst;
  } else if ((i -= 373248) < 93312) {
    lvl = 2; dst = (size_t)4852224 + i; src = dst;
  } else if ((i -= 93312) < 23328) {
    lvl = 3; dst = (size_t)6438528 + i; src = dst;
  } else if ((i -= 23328) < 5832) {
    lvl = 4; dst = (size_t)7954848 + i; src = dst;
  } else if ((i -= 5832) < 1458) {
    lvl = 5; dst = (size_t)9453672 + i; src = dst;
  } else {
    return;
  }
  const float m = __int_as_float((int)slots[lvl]);
  out[dst] = out[src] / m;
}

// Last 6 dw0 elements alias the slot bytes: read slot0 first, then write.
__global__ __launch_bounds__(64) void k_norm0_tail(
    float* __restrict__ out, const unsigned int* __restrict__ slots) {
  const float m = __int_as_float((int)slots[0]);
  if (threadIdx.x < 6) {
    const int t = 1492986 + threadIdx.x;
    out[t] = out[1492992 + t] / m;
  }
}

extern "C" void kernel_launch(void* const* d_in, const int* in_sizes, int n_in,
                              void* d_out, int out_size, void* d_ws,
                              size_t ws_size, hipStream_t stream) {
  const float* x[6];
  const float* xp[6];
  for (int i = 0; i < 6; ++i) {
    x[i] = (const float*)d_in[2 * i];
    xp[i] = (const float*)d_in[2 * i + 1];
  }
  float* out = (float*)d_out;

  float* maxbuf = out + 1400000;                         // 34992
  unsigned int* slots = (unsigned int*)(out + 1492986);  // 24 B
  bf16* part0 = (bf16*)(out + 2985984);                  // ends f32 8957952
  bf16* part1 = (bf16*)(out + 8957952);                  // ends f32 10801152

  const int NORM_TOTAL = 1492986 + 373248 + 93312 + 23328 + 5832 + 1458;

  k_part_all<<<dim3(1808), dim3(256), 0, stream>>>(
      x[0], xp[0], x[1], xp[1], x[2], xp[2], x[3], xp[3], x[4], xp[4], x[5],
      xp[5], part0, part1, out);
  k_red2<<<dim3(6336), dim3(256), 0, stream>>>(part0, part1, out, maxbuf);
  k_expand_all<<<dim3(5832, 5), dim3(256), 0, stream>>>(out, maxbuf);
  k_finmax<<<dim3(6), dim3(1024), 0, stream>>>(maxbuf, slots);
  k_norm_all<<<dim3(CEIL(NORM_TOTAL, 256)), dim3(256), 0, stream>>>(out,
                                                                    slots);
  k_norm0_tail<<<dim3(1), dim3(64), 0, stream>>>(out, slots);
}